// Round 1
// baseline (6878.505 us; speedup 1.0000x reference)
//
#include <hip/hip_runtime.h>
#include <math.h>

#define BATCH 8
#define NPTS 4096
#define MM1 2048
#define MM2 512
#define KNBR 32

// ---------------- helpers ----------------
__device__ inline double shfl_xor_dbl(double v, int mask) {
    long long x = __double_as_longlong(v);
    int lo = (int)(x & 0xffffffffLL);
    int hi = (int)(x >> 32);
    lo = __shfl_xor(lo, mask, 64);
    hi = __shfl_xor(hi, mask, 64);
    return __longlong_as_double(((long long)hi << 32) | (unsigned long long)(unsigned int)lo);
}

// ---------------- FPS: one block per batch, 256 threads ----------------
// Replicates the jax scan: idx[0]=0; dist=min over selected; argmax (first-max tie-break).
// Distances in fp64 (exact for fp32 inputs) to match the numpy reference ordering.
template<int N, int PER>
__global__ __launch_bounds__(256) void fps_kernel(const float* __restrict__ pos,
                                                  int* __restrict__ out_idx,
                                                  float* __restrict__ out_pos,
                                                  int M) {
    const int b = blockIdx.x;
    const int tid = threadIdx.x;
    __shared__ float sx[N], sy[N], sz[N];
    __shared__ int s_last;
    __shared__ double s_bv[4];
    __shared__ int s_bi[4];

    const float* p = pos + (size_t)b * N * 3;
    for (int j = tid; j < N; j += 256) {
        sx[j] = p[j * 3 + 0];
        sy[j] = p[j * 3 + 1];
        sz[j] = p[j * 3 + 2];
    }
    double dist[PER];
#pragma unroll
    for (int jj = 0; jj < PER; ++jj) dist[jj] = 1e300;

    if (tid == 0) s_last = 0;
    __syncthreads();

    for (int m = 0; m < M; ++m) {
        const int last = s_last;
        if (tid == 0) {
            out_idx[b * M + m] = last;
            out_pos[(b * M + m) * 3 + 0] = sx[last];
            out_pos[(b * M + m) * 3 + 1] = sy[last];
            out_pos[(b * M + m) * 3 + 2] = sz[last];
        }
        const double lx = (double)sx[last];
        const double ly = (double)sy[last];
        const double lz = (double)sz[last];

        double bv = -1.0;
        int bi = 0x7fffffff;
#pragma unroll
        for (int jj = 0; jj < PER; ++jj) {
            const int j = tid + jj * 256;
            const double dx = (double)sx[j] - lx;
            const double dy = (double)sy[j] - ly;
            const double dz = (double)sz[j] - lz;
            const double dd = dx * dx + dy * dy + dz * dz;
            double dc = dist[jj];
            const double dm = (dd < dc) ? dd : dc;
            dist[jj] = dm;
            // strict > keeps the earlier (smaller) index on ties == jnp.argmax
            if (dm > bv) { bv = dm; bi = j; }
        }
        // wave (64-lane) argmax reduce, tie-break to smaller index
#pragma unroll
        for (int off = 32; off > 0; off >>= 1) {
            const double ov = shfl_xor_dbl(bv, off);
            const int oi = __shfl_xor(bi, off, 64);
            if (ov > bv || (ov == bv && oi < bi)) { bv = ov; bi = oi; }
        }
        const int wid = tid >> 6;
        if ((tid & 63) == 0) { s_bv[wid] = bv; s_bi[wid] = bi; }
        __syncthreads();
        if (tid == 0) {
            double v = s_bv[0];
            int i = s_bi[0];
#pragma unroll
            for (int w = 1; w < 4; ++w) {
                if (s_bv[w] > v || (s_bv[w] == v && s_bi[w] < i)) { v = s_bv[w]; i = s_bi[w]; }
            }
            s_last = i;
        }
        __syncthreads();
    }
}

// ---------------- generic Linear (+opt ReLU) ----------------
__global__ __launch_bounds__(256) void linear_kernel(const float* __restrict__ in,
                                                     const float* __restrict__ W,
                                                     const float* __restrict__ bias,
                                                     float* __restrict__ out,
                                                     int P, int CI, int CO, int relu) {
    const int gid = blockIdx.x * blockDim.x + threadIdx.x;
    if (gid >= P * CO) return;
    const int p = gid / CO;
    const int co = gid - p * CO;
    const float* ip = in + (size_t)p * CI;
    float acc = bias[co];
    for (int i = 0; i < CI; ++i) acc = fmaf(ip[i], W[(size_t)i * CO + co], acc);
    if (relu) acc = fmaxf(acc, 0.0f);
    out[gid] = acc;
}

// ---------------- ball query: 1 thread per center, exact top-32 by (d2, idx) ----------------
template<int N>
__global__ __launch_bounds__(256) void ballq_kernel(const float* __restrict__ pos,
                                                    const float* __restrict__ ctr,
                                                    int* __restrict__ nbr,
                                                    int M, double rr) {
    const int b = blockIdx.y;
    const int m = blockIdx.x * blockDim.x + threadIdx.x;
    __shared__ float sx[N], sy[N], sz[N];
    const float* p = pos + (size_t)b * N * 3;
    for (int j = threadIdx.x; j < N; j += 256) {
        sx[j] = p[j * 3 + 0];
        sy[j] = p[j * 3 + 1];
        sz[j] = p[j * 3 + 2];
    }
    __syncthreads();
    if (m >= M) return;

    const double cx = (double)ctr[(b * M + m) * 3 + 0];
    const double cy = (double)ctr[(b * M + m) * 3 + 1];
    const double cz = (double)ctr[(b * M + m) * 3 + 2];

    double kd[KNBR];
    int ki[KNBR];
#pragma unroll
    for (int k = 0; k < KNBR; ++k) { kd[k] = 1e300; ki[k] = k; }
    double wd = 1e300;  // current worst (lexicographic max of (d2, idx))
    int wi = KNBR - 1;

    for (int n = 0; n < N; ++n) {
        const double dx = (double)sx[n] - cx;
        const double dy = (double)sy[n] - cy;
        const double dz = (double)sz[n] - cz;
        const double d2 = dx * dx + dy * dy + dz * dz;
        if (d2 <= rr) {
            if (d2 < wd || (d2 == wd && n < wi)) {
                bool done = false;
#pragma unroll
                for (int k = 0; k < KNBR; ++k) {
                    const bool hit = (!done) && (kd[k] == wd) && (ki[k] == wi);
                    if (hit) { kd[k] = d2; ki[k] = n; done = true; }
                }
                wd = -1.0; wi = -1;
#pragma unroll
                for (int k = 0; k < KNBR; ++k) {
                    if (kd[k] > wd || (kd[k] == wd && ki[k] > wi)) { wd = kd[k]; wi = ki[k]; }
                }
            }
        }
    }
#pragma unroll
    for (int k = 0; k < KNBR; ++k)
        nbr[((size_t)(b * M + m)) * KNBR + k] = (kd[k] < 1e300) ? ki[k] : -1;
}

// ---------------- max aggregation: one wave per center ----------------
__global__ __launch_bounds__(256) void agg_kernel(const float* __restrict__ h,
                                                  const int* __restrict__ nbr,
                                                  float* __restrict__ out,
                                                  int N, int M, int C) {
    const int wave = (blockIdx.x * blockDim.x + threadIdx.x) >> 6;
    const int lane = threadIdx.x & 63;
    if (wave >= BATCH * M) return;
    const int b = wave / M;
    const int m = wave - b * M;
    const int* nb = nbr + (size_t)(b * M + m) * KNBR;
    for (int c = lane; c < C; c += 64) {
        float acc = -INFINITY;
        for (int k = 0; k < KNBR; ++k) {
            const int idx = nb[k];
            if (idx >= 0) acc = fmaxf(acc, h[((size_t)b * N + idx) * C + c]);
        }
        out[((size_t)(b * M + m)) * C + c] = acc;
    }
}

// ---------------- head: global max pool + MLPs + log_softmax, one block per batch ----------------
__global__ __launch_bounds__(256) void head_kernel(const float* __restrict__ x2,
                                                   const float* __restrict__ w3a, const float* __restrict__ b3a,
                                                   const float* __restrict__ w3b, const float* __restrict__ b3b,
                                                   const float* __restrict__ fc1w, const float* __restrict__ fc1b,
                                                   const float* __restrict__ fc2w, const float* __restrict__ fc2b,
                                                   float* __restrict__ out) {
    const int b = blockIdx.x;
    const int tid = threadIdx.x;
    __shared__ float g[128], t1[256], t2[512], t3[256], logits[16];

    if (tid < 128) {
        float acc = -INFINITY;
        for (int m = 0; m < MM2; ++m) acc = fmaxf(acc, x2[((size_t)(b * MM2 + m)) * 128 + tid]);
        g[tid] = acc;
    }
    __syncthreads();
    {   // 128 -> 256, relu
        float acc = b3a[tid];
        for (int i = 0; i < 128; ++i) acc = fmaf(g[i], w3a[i * 256 + tid], acc);
        t1[tid] = fmaxf(acc, 0.0f);
    }
    __syncthreads();
    for (int c = tid; c < 512; c += 256) {  // 256 -> 512, no relu (last layer of mlp2)
        float acc = b3b[c];
        for (int i = 0; i < 256; ++i) acc = fmaf(t1[i], w3b[i * 512 + c], acc);
        t2[c] = acc;
    }
    __syncthreads();
    {   // 512 -> 256, relu
        float acc = fc1b[tid];
        for (int i = 0; i < 512; ++i) acc = fmaf(t2[i], fc1w[i * 256 + tid], acc);
        t3[tid] = fmaxf(acc, 0.0f);
    }
    __syncthreads();
    if (tid < 10) {  // 256 -> 10
        float acc = fc2b[tid];
        for (int i = 0; i < 256; ++i) acc = fmaf(t3[i], fc2w[i * 10 + tid], acc);
        logits[tid] = acc;
    }
    __syncthreads();
    if (tid == 0) {
        float mx = logits[0];
        for (int i = 1; i < 10; ++i) mx = fmaxf(mx, logits[i]);
        float s = 0.0f;
        for (int i = 0; i < 10; ++i) s += expf(logits[i] - mx);
        const float lse = mx + logf(s);
        for (int i = 0; i < 10; ++i) out[b * 10 + i] = logits[i] - lse;
    }
}

extern "C" void kernel_launch(void* const* d_in, const int* in_sizes, int n_in,
                              void* d_out, int out_size, void* d_ws, size_t ws_size,
                              hipStream_t stream) {
    const float* pos  = (const float*)d_in[0];
    const float* w1a  = (const float*)d_in[1];
    const float* b1a  = (const float*)d_in[2];
    const float* w1b  = (const float*)d_in[3];
    const float* b1b  = (const float*)d_in[4];
    const float* w2a  = (const float*)d_in[5];
    const float* b2a  = (const float*)d_in[6];
    const float* w2b  = (const float*)d_in[7];
    const float* b2b  = (const float*)d_in[8];
    const float* w3a  = (const float*)d_in[9];
    const float* b3a  = (const float*)d_in[10];
    const float* w3b  = (const float*)d_in[11];
    const float* b3b  = (const float*)d_in[12];
    const float* fc1w = (const float*)d_in[13];
    const float* fc1b = (const float*)d_in[14];
    const float* fc2w = (const float*)d_in[15];
    const float* fc2b = (const float*)d_in[16];

    char* ws = (char*)d_ws;
    int*   idx1 = (int*)  (ws + 0);                 //  64 KB  [8,2048]
    float* pos1 = (float*)(ws + (64 << 10));        // 192 KB  [8,2048,3]
    int*   idx2 = (int*)  (ws + (256 << 10));       //  16 KB  [8,512]
    float* pos2 = (float*)(ws + (272 << 10));       //  48 KB  [8,512,3]
    int*   nbr1 = (int*)  (ws + (320 << 10));       //   2 MB  [8,2048,32]
    int*   nbr2 = (int*)  (ws + (2368 << 10));      // 512 KB  [8,512,32]
    float* x1   = (float*)(ws + (3  << 20));        //   4 MB  [8,2048,64]
    float* x2   = (float*)(ws + (7  << 20));        //   2 MB  [8,512,128]
    float* t    = (float*)(ws + (9  << 20));        //   8 MB  hidden activations
    float* h    = (float*)(ws + (17 << 20));        //   8 MB  transformed features

    // ---- SA module 1: N=4096 -> M=2048, r=0.2 ----
    fps_kernel<NPTS, NPTS / 256><<<BATCH, 256, 0, stream>>>(pos, idx1, pos1, MM1);
    {
        const int P = BATCH * NPTS;
        linear_kernel<<<(P * 64 + 255) / 256, 256, 0, stream>>>(pos, w1a, b1a, t, P, 3, 64, 1);
        linear_kernel<<<(P * 64 + 255) / 256, 256, 0, stream>>>(t, w1b, b1b, h, P, 64, 64, 0);
    }
    {
        dim3 g(MM1 / 256, BATCH);
        ballq_kernel<NPTS><<<g, 256, 0, stream>>>(pos, pos1, nbr1, MM1, 0.2 * 0.2);
    }
    agg_kernel<<<(BATCH * MM1) / 4, 256, 0, stream>>>(h, nbr1, x1, NPTS, MM1, 64);

    // ---- SA module 2: N=2048 -> M=512, r=0.4 ----
    fps_kernel<MM1, MM1 / 256><<<BATCH, 256, 0, stream>>>(pos1, idx2, pos2, MM2);
    {
        const int P = BATCH * MM1;
        linear_kernel<<<(P * 128 + 255) / 256, 256, 0, stream>>>(x1, w2a, b2a, t, P, 64, 128, 1);
        linear_kernel<<<(P * 128 + 255) / 256, 256, 0, stream>>>(t, w2b, b2b, h, P, 128, 128, 0);
    }
    {
        dim3 g(MM2 / 256, BATCH);
        ballq_kernel<MM1><<<g, 256, 0, stream>>>(pos1, pos2, nbr2, MM2, 0.4 * 0.4);
    }
    agg_kernel<<<(BATCH * MM2) / 4, 256, 0, stream>>>(h, nbr2, x2, MM1, MM2, 128);

    // ---- head ----
    head_kernel<<<BATCH, 256, 0, stream>>>(x2, w3a, b3a, w3b, b3b, fc1w, fc1b, fc2w, fc2b,
                                           (float*)d_out);
}